// Round 1
// baseline (1794.348 us; speedup 1.0000x reference)
//
#include <hip/hip_runtime.h>
#include <hip/hip_fp16.h>

typedef _Float16 half8 __attribute__((ext_vector_type(8)));
typedef float floatx4 __attribute__((ext_vector_type(4)));

// d_ws half-element layout (packed fragment-major, hi then lo per layer)
#define W1H_OFF 0
#define W1L_OFF 32768
#define W2H_OFF 65536
#define W2L_OFF 131072
#define W3H_OFF 196608
#define W3L_OFF 212992
// total halfs = 229376 (458752 bytes)

__device__ __forceinline__ floatx4 mfma16(half8 a, half8 b, floatx4 c) {
    return __builtin_amdgcn_mfma_f32_16x16x32_f16(a, b, c, 0, 0, 0);
}

// Tsitouras 5(4): row s gives coefficients for combine after eval s
// (s=0..4 -> stage inputs 2..6; s=5 -> final B weights)
__device__ const float dCoef[6][6] = {
    {0.161f, 0.f, 0.f, 0.f, 0.f, 0.f},
    {-0.008480655492356989f, 0.335480655492357f, 0.f, 0.f, 0.f, 0.f},
    {2.8971530571054935f, -6.359448489975075f, 4.3622954328695815f, 0.f, 0.f, 0.f},
    {5.325864828439257f, -11.748883564062828f, 7.4955393428898365f, -0.09249506636175525f, 0.f, 0.f},
    {5.86145544294642f, -12.92096931784711f, 8.159367898576159f, -0.071584973281401f, -0.028269050394068383f, 0.f},
    {0.09646076681806523f, 0.01f, 0.4798896504144996f, 1.379008574103742f, -3.290069515436081f, 2.324710524099774f},
};

// Pack W[n][k] (row-major [N][K] fp32) into MFMA-B fragment-major fp16 hi/lo:
// ws[off + ((kk*NT + tn)*64 + lane)*8 + j] = W[tn*16 + (lane&15)][kk*32 + (lane>>4)*8 + j]
__global__ __launch_bounds__(256) void pack_weights(
    const float* __restrict__ W1, const float* __restrict__ W2,
    const float* __restrict__ W3, _Float16* __restrict__ ws)
{
    int e = blockIdx.x * 256 + threadIdx.x;  // 0..114687
    const float* W;
    int K, NT, hoff, loff, eb = e;
    if (e < 32768)      { W = W1; K = 128; NT = 16; hoff = W1H_OFF; loff = W1L_OFF; }
    else if (e < 98304) { W = W2; K = 256; NT = 16; hoff = W2H_OFF; loff = W2L_OFF; eb = e - 32768; }
    else                { W = W3; K = 256; NT = 4;  hoff = W3H_OFF; loff = W3L_OFF; eb = e - 98304; }
    int j = eb & 7, l = (eb >> 3) & 63, t = eb >> 9;
    int tn = t % NT, kk = t / NT;
    int n = tn * 16 + (l & 15);
    int k = kk * 32 + ((l >> 4) * 8) + j;
    float wv = W[n * K + k];
    _Float16 hi = (_Float16)wv;
    _Float16 lo = (_Float16)(wv - (float)hi);
    ws[hoff + eb] = hi;
    ws[loff + eb] = lo;
}

// swizzled LDS activation fragment read: element idx = (row*K + k0) ^ ((row&7)<<3)
__device__ __forceinline__ half8 lds_frag(const _Float16* s, int K, int row, int k0) {
    int idx = (row * K + k0) ^ ((row & 7) << 3);
    return *reinterpret_cast<const half8*>(s + idx);
}

__global__ __launch_bounds__(512) void ode_kernel(
    const float* __restrict__ x0, const float* __restrict__ u,
    const float* __restrict__ b1, const float* __restrict__ b2,
    const float* __restrict__ b3, const _Float16* __restrict__ ws,
    const int* __restrict__ t0p, const int* __restrict__ t1p,
    float* __restrict__ out)
{
    __shared__ float sY[16 * 64];
    __shared__ float sKf[6 * 16 * 64];
    __shared__ _Float16 sZh[16 * 128], sZl[16 * 128];
    __shared__ _Float16 sA1h[16 * 256], sA1l[16 * 256];
    __shared__ _Float16 sA2h[16 * 256], sA2l[16 * 256];
    __shared__ _Float16 sW3[2 * 16384];  // packed fragment-major: hi @0, lo @16384
    __shared__ float sB1[256], sB2[256], sB3[64];

    const int tid = threadIdx.x;
    const int lane = tid & 63;
    const int w = tid >> 6;           // wave id 0..7
    const int r0 = blockIdx.x * 16;   // this block's batch rows [r0, r0+16)

    // ---- one-time init ----
    if (tid < 256) sB1[tid] = b1[tid];
    else sB2[tid - 256] = b2[tid - 256];
    if (tid < 64) sB3[tid] = b3[tid];
    {   // cache packed W3 (hi+lo) in LDS: 4096 half8 chunks
        const half8* src = reinterpret_cast<const half8*>(ws + W3H_OFF);
        half8* dst = reinterpret_cast<half8*>(sW3);
        for (int i = tid; i < 4096; i += 512) dst[i] = src[i];
    }
    {   // y, z(y|u) init; 2 contiguous elems per thread
        int row = tid >> 5, c0 = (tid & 31) * 2;
        float y0v = x0[(r0 + row) * 64 + c0], y1v = x0[(r0 + row) * 64 + c0 + 1];
        float u0v = u[(r0 + row) * 64 + c0], u1v = u[(r0 + row) * 64 + c0 + 1];
        sY[row * 64 + c0] = y0v;
        sY[row * 64 + c0 + 1] = y1v;
        int zy = (row * 128 + c0) ^ ((row & 7) << 3);
        int zu = (row * 128 + 64 + c0) ^ ((row & 7) << 3);
        _Float16 h0 = (_Float16)y0v, h1 = (_Float16)y1v;
        sZh[zy] = h0; sZh[zy + 1] = h1;
        sZl[zy] = (_Float16)(y0v - (float)h0);
        sZl[zy + 1] = (_Float16)(y1v - (float)h1);
        _Float16 g0 = (_Float16)u0v, g1 = (_Float16)u1v;
        sZh[zu] = g0; sZh[zu + 1] = g1;
        sZl[zu] = (_Float16)(u0v - (float)g0);
        sZl[zu + 1] = (_Float16)(u1v - (float)g1);
    }
    __syncthreads();

    const int nsteps = (t1p[0] - t0p[0]) * 60;  // h = 60s = 1/60 hr
    const float H = 1.0f / 60.0f;

    const half8* w1h = reinterpret_cast<const half8*>(ws + W1H_OFF);
    const half8* w1l = reinterpret_cast<const half8*>(ws + W1L_OFF);
    const half8* w2h = reinterpret_cast<const half8*>(ws + W2H_OFF);
    const half8* w2l = reinterpret_cast<const half8*>(ws + W2L_OFF);
    const half8* w3h = reinterpret_cast<const half8*>(sW3);
    const half8* w3l = reinterpret_cast<const half8*>(sW3 + 16384);

    const int arow = lane & 15;
    const int kb = (lane >> 4) * 8;

    #pragma unroll 1
    for (int step = 0; step < nsteps; ++step) {
        #pragma unroll 1
        for (int stg = 0; stg < 6; ++stg) {
            // ---------- Layer 1: [16x128] z @ W1^T -> relu -> sA1 [16x256] ----------
            {
                floatx4 acc[2][2] = {{{0.f,0.f,0.f,0.f},{0.f,0.f,0.f,0.f}},
                                     {{0.f,0.f,0.f,0.f},{0.f,0.f,0.f,0.f}}};
                #pragma unroll
                for (int kk = 0; kk < 4; ++kk) {
                    half8 ah = lds_frag(sZh, 128, arow, kb + kk * 32);
                    half8 al = lds_frag(sZl, 128, arow, kb + kk * 32);
                    #pragma unroll
                    for (int t = 0; t < 2; ++t) {
                        int fi = (kk * 16 + (2 * w + t)) * 64 + lane;
                        half8 bh = w1h[fi];
                        half8 bl = w1l[fi];
                        acc[t][kk & 1] = mfma16(ah, bh, acc[t][kk & 1]);
                        acc[t][kk & 1] = mfma16(ah, bl, acc[t][kk & 1]);
                        acc[t][kk & 1] = mfma16(al, bh, acc[t][kk & 1]);
                    }
                }
                #pragma unroll
                for (int t = 0; t < 2; ++t) {
                    int col = (lane & 15) + (2 * w + t) * 16;
                    float bb = sB1[col];
                    #pragma unroll
                    for (int r = 0; r < 4; ++r) {
                        int orow = (lane >> 4) * 4 + r;
                        float v = acc[t][0][r] + acc[t][1][r] + bb;
                        v = fmaxf(v, 0.0f);
                        _Float16 hi = (_Float16)v, lo = (_Float16)(v - (float)hi);
                        int idx = (orow * 256 + col) ^ ((orow & 7) << 3);
                        sA1h[idx] = hi;
                        sA1l[idx] = lo;
                    }
                }
            }
            __syncthreads();
            // ---------- Layer 2: [16x256] a1 @ W2^T -> relu -> sA2 [16x256] ----------
            {
                floatx4 acc[2][2] = {{{0.f,0.f,0.f,0.f},{0.f,0.f,0.f,0.f}},
                                     {{0.f,0.f,0.f,0.f},{0.f,0.f,0.f,0.f}}};
                #pragma unroll
                for (int kk = 0; kk < 8; ++kk) {
                    half8 ah = lds_frag(sA1h, 256, arow, kb + kk * 32);
                    half8 al = lds_frag(sA1l, 256, arow, kb + kk * 32);
                    #pragma unroll
                    for (int t = 0; t < 2; ++t) {
                        int fi = (kk * 16 + (2 * w + t)) * 64 + lane;
                        half8 bh = w2h[fi];
                        half8 bl = w2l[fi];
                        acc[t][kk & 1] = mfma16(ah, bh, acc[t][kk & 1]);
                        acc[t][kk & 1] = mfma16(ah, bl, acc[t][kk & 1]);
                        acc[t][kk & 1] = mfma16(al, bh, acc[t][kk & 1]);
                    }
                }
                #pragma unroll
                for (int t = 0; t < 2; ++t) {
                    int col = (lane & 15) + (2 * w + t) * 16;
                    float bb = sB2[col];
                    #pragma unroll
                    for (int r = 0; r < 4; ++r) {
                        int orow = (lane >> 4) * 4 + r;
                        float v = acc[t][0][r] + acc[t][1][r] + bb;
                        v = fmaxf(v, 0.0f);
                        _Float16 hi = (_Float16)v, lo = (_Float16)(v - (float)hi);
                        int idx = (orow * 256 + col) ^ ((orow & 7) << 3);
                        sA2h[idx] = hi;
                        sA2l[idx] = lo;
                    }
                }
            }
            __syncthreads();
            // ---------- Layer 3: [16x256] a2 @ W3^T -> sK[stg] [16x64] (waves 0-3) ----------
            if (w < 4) {
                floatx4 aE = {0.f, 0.f, 0.f, 0.f}, aO = {0.f, 0.f, 0.f, 0.f};
                #pragma unroll
                for (int kk = 0; kk < 8; ++kk) {
                    half8 ah = lds_frag(sA2h, 256, arow, kb + kk * 32);
                    half8 al = lds_frag(sA2l, 256, arow, kb + kk * 32);
                    int fi = (kk * 4 + w) * 64 + lane;
                    half8 bh = w3h[fi];
                    half8 bl = w3l[fi];
                    if (kk & 1) {
                        aO = mfma16(ah, bh, aO); aO = mfma16(ah, bl, aO); aO = mfma16(al, bh, aO);
                    } else {
                        aE = mfma16(ah, bh, aE); aE = mfma16(ah, bl, aE); aE = mfma16(al, bh, aE);
                    }
                }
                int col = (lane & 15) + 16 * w;
                float bb = sB3[col];
                #pragma unroll
                for (int r = 0; r < 4; ++r) {
                    int orow = (lane >> 4) * 4 + r;
                    sKf[stg * 1024 + orow * 64 + col] = aE[r] + aO[r] + bb;
                }
            }
            __syncthreads();
            // ---------- RK combine: z_next = y + H * sum_j coef[stg][j]*k_j ----------
            {
                int row = tid >> 5, c0 = (tid & 31) * 2;
                float acc0 = 0.f, acc1 = 0.f;
                for (int j = 0; j <= stg; ++j) {
                    float a = dCoef[stg][j];
                    acc0 += a * sKf[j * 1024 + row * 64 + c0];
                    acc1 += a * sKf[j * 1024 + row * 64 + c0 + 1];
                }
                float z0 = sY[row * 64 + c0] + H * acc0;
                float z1 = sY[row * 64 + c0 + 1] + H * acc1;
                if (stg == 5) {  // final combine of the step: update y
                    sY[row * 64 + c0] = z0;
                    sY[row * 64 + c0 + 1] = z1;
                }
                int zy = (row * 128 + c0) ^ ((row & 7) << 3);
                _Float16 h0 = (_Float16)z0, h1 = (_Float16)z1;
                sZh[zy] = h0; sZh[zy + 1] = h1;
                sZl[zy] = (_Float16)(z0 - (float)h0);
                sZl[zy + 1] = (_Float16)(z1 - (float)h1);
            }
            __syncthreads();
        }
    }
    // ---- write y_final ----
    {
        int row = tid >> 5, c0 = (tid & 31) * 2;
        out[(r0 + row) * 64 + c0] = sY[row * 64 + c0];
        out[(r0 + row) * 64 + c0 + 1] = sY[row * 64 + c0 + 1];
    }
}

extern "C" void kernel_launch(void* const* d_in, const int* in_sizes, int n_in,
                              void* d_out, int out_size, void* d_ws, size_t ws_size,
                              hipStream_t stream)
{
    const float* x0 = (const float*)d_in[0];
    const float* u  = (const float*)d_in[1];
    const float* W1 = (const float*)d_in[2];
    const float* b1 = (const float*)d_in[3];
    const float* W2 = (const float*)d_in[4];
    const float* b2 = (const float*)d_in[5];
    const float* W3 = (const float*)d_in[6];
    const float* b3 = (const float*)d_in[7];
    const int* t0 = (const int*)d_in[8];
    const int* t1 = (const int*)d_in[9];
    float* out = (float*)d_out;
    _Float16* ws = (_Float16*)d_ws;

    // 1) pack weights into fragment-major fp16 hi/lo (re-done every call; deterministic)
    pack_weights<<<448, 256, 0, stream>>>(W1, W2, W3, ws);
    // 2) persistent ODE solve: 64 blocks x 16 rows, all 60 steps in one launch
    ode_kernel<<<64, 512, 0, stream>>>(x0, u, b1, b2, b3, ws, t0, t1, out);
}